// Round 13
// baseline (3355.674 us; speedup 1.0000x reference)
//
#include <hip/hip_runtime.h>
#include <hip/hip_bf16.h>
#include <math.h>

#define SLEN 2048
#define DDIM 512
#define BNUM 8
#define MTOT (BNUM * SLEN)   // 16384

typedef float f32x4 __attribute__((ext_vector_type(4)));
typedef short s16x8 __attribute__((ext_vector_type(8)));   // 8 bf16 (4 VGPRs)

// fp32 -> bf16 (RNE) as raw ushort
__device__ __forceinline__ unsigned short f2bf(float f) {
    unsigned u = __float_as_uint(f);
    u += 0x7FFFu + ((u >> 16) & 1u);
    return (unsigned short)(u >> 16);
}

// ---------------------------------------------------------------------------
// Coherence helpers. Two proven facts drive the design:
//  (r8)  sc0 LOADS have Shader-Engine scope -> stale cross-CU. sc1 = device.
//  (r12) issue and waitcnt of a comm load MUST be in ONE asm block, else
//        hipcc inserts register copies that read in-flight destinations.
// sc1 path (always correct): store sc1 / load sc1 -> coherent at LLC.
// L2 fast path (only when all 8 WGs of a batch share an XCD, runtime-
// verified): publish = plain store (vector L1 is write-through -> lands in
// the XCD L2); poll = global_atomic_add_x2 of 0 with sc0-return (atomics
// are never performed in L1; they execute at the L2) -> both meet at the
// XCD L2 (~250cy RT vs ~700 at LLC).
// ---------------------------------------------------------------------------
__device__ __forceinline__ void st_u64_sc1(uint2* p, uint2 v) {
    asm volatile("global_store_dwordx2 %0, %1, off sc1"
                 :: "v"(p), "v"(v) : "memory");
}
__device__ __forceinline__ uint2 ld_u64_sc1(const uint2* p) {
    uint2 v;
    asm volatile("global_load_dwordx2 %0, %1, off sc1\n\ts_waitcnt vmcnt(0)"
                 : "=v"(v) : "v"(p) : "memory");
    return v;
}
__device__ __forceinline__ void st_u64_plain(uint2* p, uint2 v) {
    asm volatile("global_store_dwordx2 %0, %1, off"
                 :: "v"(p), "v"(v) : "memory");
}
__device__ __forceinline__ uint2 poll_once_l2(uint2* p) {
    uint2 v; uint2 z; z.x = 0u; z.y = 0u;
    asm volatile("global_atomic_add_x2 %0, %1, %2, off sc0\n\ts_waitcnt vmcnt(0)"
                 : "=v"(v) : "v"(p), "v"(z) : "memory");
    return v;
}
__device__ __forceinline__ void scrub_slot_l2(uint2* p) {
    uint2 old; uint2 z; z.x = 0u; z.y = 0u;
    asm volatile("global_atomic_swap_x2 %0, %1, %2, off sc0\n\ts_waitcnt vmcnt(0)"
                 : "=v"(old) : "v"(p), "v"(z) : "memory");
    asm volatile("" :: "v"(old));
}

#define NTAGCLR (2 * BNUM * 512 + 64 + 64)   // stateTag + xcdtag + scrubdone

// ---------------------------------------------------------------------------
// Kernel 0: clear all protocol buffers through the sc1 (LLC) path.
// ---------------------------------------------------------------------------
__global__ __launch_bounds__(512) void clear_tags_kernel(uint2* buf)
{
    int i = blockIdx.x * 512 + threadIdx.x;
    if (i < NTAGCLR) {
        uint2 z; z.x = 0u; z.y = 0u;
        st_u64_sc1(&buf[i], z);
    }
}

// ---------------------------------------------------------------------------
// Kernel A: fused precompute GEMM via bf16 MFMA (round-10, proven).
// ---------------------------------------------------------------------------
__global__ __launch_bounds__(256) void precompute_kernel(
    const float* __restrict__ x,
    const float* __restrict__ Wu, const float* __restrict__ bu,
    const float* __restrict__ Wa, const float* __restrict__ ba,
    const float* __restrict__ Wc, const float* __restrict__ bc,
    const float* __restrict__ Wg, const float* __restrict__ bg,
    float* __restrict__ gbuf, float* __restrict__ cosb,
    float* __restrict__ sinb, float* __restrict__ cdbuf,
    float* __restrict__ ogout)
{
    __shared__ unsigned short As[128 * 40];
    __shared__ unsigned short Bs[128 * 40];

    const int bn = blockIdx.x * 128;      // 0..1791 in steps of 128
    const int bm = blockIdx.y * 128;      // 0..16383

    const float* W; const float* bias; int mode; int dcol;
    if (bn < 512)       { W = Wu; bias = bu; mode = 0; dcol = bn; }
    else if (bn < 768)  { W = Wa; bias = ba; mode = 1; dcol = bn - 512; }
    else if (bn < 1280) { W = Wc; bias = bc; mode = 2; dcol = bn - 768; }
    else                { W = Wg; bias = bg; mode = 3; dcol = bn - 1280; }

    const int tid  = threadIdx.x;
    const int lane = tid & 63, wv = tid >> 6;
    const int wm = wv >> 1, wn = wv & 1;
    const int lr  = lane & 15;
    const int lkb = (lane >> 4) * 8;      // ushort offset of the 8-k group

    f32x4 acc[4][4];
    #pragma unroll
    for (int i = 0; i < 4; ++i)
        #pragma unroll
        for (int j = 0; j < 4; ++j)
            acc[i][j] = (f32x4){0.f, 0.f, 0.f, 0.f};

    const int r = tid >> 1, h = tid & 1;  // staging: row, k-half
    const float* aSrc = x + (size_t)(bm + r) * DDIM + h * 16;
    const float* bSrc = W + (size_t)(dcol + r) * DDIM + h * 16;
    unsigned short* aDst = &As[r * 40 + h * 16];
    unsigned short* bDst = &Bs[r * 40 + h * 16];

    for (int kt = 0; kt < 16; ++kt) {
        {
            float4 fa0 = *(const float4*)(aSrc + 0);
            float4 fa1 = *(const float4*)(aSrc + 4);
            float4 fa2 = *(const float4*)(aSrc + 8);
            float4 fa3 = *(const float4*)(aSrc + 12);
            union { unsigned short u[8]; s16x8 v; } pa0, pa1;
            pa0.u[0]=f2bf(fa0.x); pa0.u[1]=f2bf(fa0.y); pa0.u[2]=f2bf(fa0.z); pa0.u[3]=f2bf(fa0.w);
            pa0.u[4]=f2bf(fa1.x); pa0.u[5]=f2bf(fa1.y); pa0.u[6]=f2bf(fa1.z); pa0.u[7]=f2bf(fa1.w);
            pa1.u[0]=f2bf(fa2.x); pa1.u[1]=f2bf(fa2.y); pa1.u[2]=f2bf(fa2.z); pa1.u[3]=f2bf(fa2.w);
            pa1.u[4]=f2bf(fa3.x); pa1.u[5]=f2bf(fa3.y); pa1.u[6]=f2bf(fa3.z); pa1.u[7]=f2bf(fa3.w);
            *(s16x8*)(aDst + 0) = pa0.v;
            *(s16x8*)(aDst + 8) = pa1.v;

            float4 fb0 = *(const float4*)(bSrc + 0);
            float4 fb1 = *(const float4*)(bSrc + 4);
            float4 fb2 = *(const float4*)(bSrc + 8);
            float4 fb3 = *(const float4*)(bSrc + 12);
            union { unsigned short u[8]; s16x8 v; } pb0, pb1;
            pb0.u[0]=f2bf(fb0.x); pb0.u[1]=f2bf(fb0.y); pb0.u[2]=f2bf(fb0.z); pb0.u[3]=f2bf(fb0.w);
            pb0.u[4]=f2bf(fb1.x); pb0.u[5]=f2bf(fb1.y); pb0.u[6]=f2bf(fb1.z); pb0.u[7]=f2bf(fb1.w);
            pb1.u[0]=f2bf(fb2.x); pb1.u[1]=f2bf(fb2.y); pb1.u[2]=f2bf(fb2.z); pb1.u[3]=f2bf(fb2.w);
            pb1.u[4]=f2bf(fb3.x); pb1.u[5]=f2bf(fb3.y); pb1.u[6]=f2bf(fb3.z); pb1.u[7]=f2bf(fb3.w);
            *(s16x8*)(bDst + 0) = pb0.v;
            *(s16x8*)(bDst + 8) = pb1.v;

            aSrc += 32; bSrc += 32;
        }
        __syncthreads();

        s16x8 af[4], bf[4];
        #pragma unroll
        for (int i = 0; i < 4; ++i)
            af[i] = *(const s16x8*)&As[(wm * 64 + i * 16 + lr) * 40 + lkb];
        #pragma unroll
        for (int j = 0; j < 4; ++j)
            bf[j] = *(const s16x8*)&Bs[(wn * 64 + j * 16 + lr) * 40 + lkb];
        #pragma unroll
        for (int i = 0; i < 4; ++i)
            #pragma unroll
            for (int j = 0; j < 4; ++j)
                acc[i][j] = __builtin_amdgcn_mfma_f32_16x16x32_bf16(
                    af[i], bf[j], acc[i][j], 0, 0, 0);
        __syncthreads();
    }

    // ---- epilogue: bias + activation ----
    const int orow = (lane >> 4) * 4;
    #pragma unroll
    for (int i = 0; i < 4; ++i) {
        #pragma unroll
        for (int j = 0; j < 4; ++j) {
            #pragma unroll
            for (int v = 0; v < 4; ++v) {
                int m  = bm + wm * 64 + i * 16 + orow + v;
                int nc = dcol + wn * 64 + j * 16 + lr;
                float val = acc[i][j][v] + bias[nc];
                if (mode == 0) {
                    gbuf[(size_t)m * 512 + nc] = 1.f / (1.f + expf(-val));
                } else if (mode == 1) {
                    cosb[(size_t)m * 256 + nc] = cosf(val);
                    sinb[(size_t)m * 256 + nc] = sinf(val);
                } else if (mode == 2) {
                    cdbuf[(size_t)m * 512 + nc] = tanhf(val);
                } else {
                    ogout[(size_t)m * 512 + nc] = 1.f / (1.f + expf(-val));
                }
            }
        }
    }
}

// ---------------------------------------------------------------------------
// Kernel B steady state (round-11 layout, proven): 64 WGs x 512 thr,
// b = wg&7, oct = wg>>3 owns rows [oct*64, +64). Lane (wave w, lane l):
// row o = oct*64 + w*8 + (l>>3), k-segment (l&7)*64. Reduce = shfl_xor
// (1,2,4) + shfl_xor(8). kseg==0 lanes rotate/gate/publish. Wave w != oct
// polls state segment w. ONE __syncthreads per step (parity-double-buffered
// stt). Gate prefetch issued AFTER the poll (round-13 fix: in round 11 the
// poll's vmcnt(0) drained the same wave's publisher-lane HBM gate loads).
// ---------------------------------------------------------------------------
template<bool FAST>
__device__ __forceinline__ void run_scan(
    int b, int oct, int tid,
    const float* __restrict__ Wt, const float* __restrict__ bt,
    const float* __restrict__ pg, const float* __restrict__ pcd,
    const float* __restrict__ pc, const float* __restrict__ psn,
    float* __restrict__ stb, uint2* stateTag, float* __restrict__ finalOut,
    float (*stt)[8][68])
{
    const int w = tid >> 6;
    const int l = tid & 63;
    const int kseg = l & 7;
    const int rl = l >> 3;
    const int o = oct * 64 + w * 8 + rl;
    const int e = w * 64 + l;
    const bool isPub = (kseg == 0);

    // register/AGPR-resident weight slice: Wt[o][kseg*64 .. +64)
    const float* wrow = Wt + (size_t)o * DDIM + kseg * 64;
    f32x4 w0  = *(const f32x4*)(wrow +  0);
    f32x4 w1  = *(const f32x4*)(wrow +  4);
    f32x4 w2  = *(const f32x4*)(wrow +  8);
    f32x4 w3  = *(const f32x4*)(wrow + 12);
    f32x4 w4  = *(const f32x4*)(wrow + 16);
    f32x4 w5  = *(const f32x4*)(wrow + 20);
    f32x4 w6  = *(const f32x4*)(wrow + 24);
    f32x4 w7  = *(const f32x4*)(wrow + 28);
    f32x4 w8  = *(const f32x4*)(wrow + 32);
    f32x4 w9  = *(const f32x4*)(wrow + 36);
    f32x4 w10 = *(const f32x4*)(wrow + 40);
    f32x4 w11 = *(const f32x4*)(wrow + 44);
    f32x4 w12 = *(const f32x4*)(wrow + 48);
    f32x4 w13 = *(const f32x4*)(wrow + 52);
    f32x4 w14 = *(const f32x4*)(wrow + 56);
    f32x4 w15 = *(const f32x4*)(wrow + 60);
    asm volatile("" : "+v"(w0), "+v"(w1), "+v"(w2),  "+v"(w3),
                      "+v"(w4), "+v"(w5), "+v"(w6),  "+v"(w7),
                      "+v"(w8), "+v"(w9), "+v"(w10), "+v"(w11),
                      "+v"(w12), "+v"(w13), "+v"(w14), "+v"(w15));

    const float btv = bt[o];

    stt[0][w][l] = 0.f;   // S_0 = 0

    float gC = 0.f, cdC = 0.f, cC = 0.f, snC = 0.f;
    if (isPub) {
        gC  = pg [o];
        cdC = pcd[o];
        cC  = pc [o >> 1];
        snC = psn[o >> 1];
    }
    __syncthreads();

    for (int s = 0; s < SLEN; ++s) {
        const int par = s & 1;

        // ---- partial over k-segment (conflict-free broadcast LDS reads) --
        float p0 = 0.f, p1 = 0.f, p2 = 0.f, p3 = 0.f;
        const float* st = &stt[par][kseg][0];
        {
            f32x4 sv;
            #define MACV(WV, OFF) \
                sv = *(const f32x4*)(st + OFF); \
                p0 = fmaf(WV.x, sv.x, p0); \
                p1 = fmaf(WV.y, sv.y, p1); \
                p2 = fmaf(WV.z, sv.z, p2); \
                p3 = fmaf(WV.w, sv.w, p3);
            MACV(w0,  0)  MACV(w1,  4)  MACV(w2,  8)  MACV(w3,  12)
            MACV(w4,  16) MACV(w5,  20) MACV(w6,  24) MACV(w7,  28)
            MACV(w8,  32) MACV(w9,  36) MACV(w10, 40) MACV(w11, 44)
            MACV(w12, 48) MACV(w13, 52) MACV(w14, 56) MACV(w15, 60)
            #undef MACV
        }
        float t = (p0 + p1) + (p2 + p3);
        t += __shfl_xor(t, 1);
        t += __shfl_xor(t, 2);
        t += __shfl_xor(t, 4);     // 8-lane group holds the full dot
        t += btv;
        float tp = __shfl_xor(t, 8);   // partner row (rl ^ 1)

        if (isPub) {
            float rot = (rl & 1) ? fmaf(tp, snC, t * cC)
                                 : fmaf(t, cC, -(tp * snC));
            float nxt = fmaf(gC, rot, (1.f - gC) * cdC);
            if (s + 1 < SLEN) {   // tag SLEN is never polled
                uint2 u; u.x = __float_as_uint(nxt); u.y = (unsigned)(s + 1);
                uint2* slot = &stateTag[((size_t)((s + 1) & 1) * BNUM + b) * 512 + o];
                if (FAST) st_u64_plain(slot, u);
                else      st_u64_sc1(slot, u);
            }
            stb[(size_t)s * 512 + o] = nxt;          // for emit kernel
            stt[par ^ 1][oct][w * 8 + rl] = nxt;     // own segment
            if (s == SLEN - 1) finalOut[b * 512 + o] = nxt;
        }
        if (w != oct && s + 1 < SLEN) {
            // ---- poll segment w for step s+1, fill other parity ----
            uint2* pp = &stateTag[((size_t)((s + 1) & 1) * BNUM + b) * 512 + e];
            uint2 u; int guard = 0;
            if (FAST) { do { u = poll_once_l2(pp); }
                        while (u.y != (unsigned)(s + 1) && ++guard < (1 << 16)); }
            else      { do { u = ld_u64_sc1(pp); }
                        while (u.y != (unsigned)(s + 1) && ++guard < (1 << 16)); }
            stt[par ^ 1][w][l] = __uint_as_float(u.x);
        }
        // gate prefetch for s+1 AFTER the poll (consumed next publish;
        // barrier + matvec cover the latency)
        if (isPub) {
            int sp1 = (s + 1) & (SLEN - 1);   // wrap harmlessly at end
            gC  = pg [(size_t)sp1 * 512 + o];
            cdC = pcd[(size_t)sp1 * 512 + o];
            cC  = pc [(size_t)sp1 * 256 + (o >> 1)];
            snC = psn[(size_t)sp1 * 256 + (o >> 1)];
        }
        __syncthreads();   // stt[par^1] complete -> next step's compute
    }
}

__global__ __launch_bounds__(512, 2) void scan_kernel(
    const float* __restrict__ Wt, const float* __restrict__ bt,
    const float* __restrict__ gbuf, const float* __restrict__ cosb,
    const float* __restrict__ sinb, const float* __restrict__ cdbuf,
    float* __restrict__ states, uint2* stateTag, uint2* xcdtag,
    uint2* scrubdone, float* __restrict__ finalOut)
{
    const int wg = blockIdx.x;
    const int b = wg & 7, oct = wg >> 3;
    const int tid = threadIdx.x;

    __shared__ float stt[2][8][68];  // [parity][segment][element], padded
    __shared__ int lds_fast;

    // ---- one-time: are this batch's 8 WGs on one XCD? (sc1 exchange) ----
    unsigned myxcd = __builtin_amdgcn_s_getreg((31u << 11) | 20u); // XCC_ID
    if (tid == 0) {
        uint2 m; m.x = myxcd; m.y = 0x5AFEu;
        st_u64_sc1(&xcdtag[wg], m);
        bool same = true;
        for (int i = 0; i < 8; ++i) {
            uint2 u; int g = 0;
            do { u = ld_u64_sc1(&xcdtag[i * 8 + b]); }
            while (u.y != 0x5AFEu && ++g < (1 << 20));
            if (u.y != 0x5AFEu || u.x != myxcd) same = false;
        }
        lds_fast = same ? 1 : 0;
    }
    __syncthreads();
    const bool fast = (lds_fast != 0);

    if (fast) {
        // Scrub ALL of this batch's slots (both parities) in the local L2:
        // atomic swap(0) overwrites any stale dirty line left by a previous
        // replay (round-3's bug at the L2 level). Each WG scrubs the whole
        // batch (redundant across the 8 WGs; idempotent zeros).
        scrub_slot_l2(&stateTag[(size_t)(0 * BNUM + b) * 512 + tid]);
        scrub_slot_l2(&stateTag[(size_t)(1 * BNUM + b) * 512 + tid]);
        __syncthreads();
        // cross-WG barrier (sc1): no publisher may start before all scrubs
        if (tid == 0) {
            uint2 m; m.x = 1u; m.y = 0xD09Eu;
            st_u64_sc1(&scrubdone[wg], m);
            for (int i = 0; i < 8; ++i) {
                uint2 u; int g = 0;
                do { u = ld_u64_sc1(&scrubdone[i * 8 + b]); }
                while (u.y != 0xD09Eu && ++g < (1 << 20));
            }
        }
        __syncthreads();
    }

    const float* pg  = gbuf  + (size_t)b * SLEN * 512;
    const float* pcd = cdbuf + (size_t)b * SLEN * 512;
    const float* pc  = cosb  + (size_t)b * SLEN * 256;
    const float* psn = sinb  + (size_t)b * SLEN * 256;
    float* stb = states + (size_t)b * SLEN * 512;

    if (fast)
        run_scan<true >(b, oct, tid, Wt, bt, pg, pcd, pc, psn,
                        stb, stateTag, finalOut, stt);
    else
        run_scan<false>(b, oct, tid, Wt, bt, pg, pcd, pc, psn,
                        stb, stateTag, finalOut, stt);
}

// ---------------------------------------------------------------------------
// Kernel C: emitted = og * (states @ Wo^T + bo) via bf16 MFMA (round-10,
// proven). og staged in d_out by kernel A; read then overwritten.
// ---------------------------------------------------------------------------
__global__ __launch_bounds__(256) void emit_kernel(
    const float* __restrict__ states, const float* __restrict__ Wo,
    const float* __restrict__ bo, float* __restrict__ out)
{
    __shared__ unsigned short As[128 * 40];
    __shared__ unsigned short Bs[128 * 40];

    const int bn = blockIdx.x * 128;
    const int bm = blockIdx.y * 128;

    const int tid  = threadIdx.x;
    const int lane = tid & 63, wv = tid >> 6;
    const int wm = wv >> 1, wn = wv & 1;
    const int lr  = lane & 15;
    const int lkb = (lane >> 4) * 8;

    f32x4 acc[4][4];
    #pragma unroll
    for (int i = 0; i < 4; ++i)
        #pragma unroll
        for (int j = 0; j < 4; ++j)
            acc[i][j] = (f32x4){0.f, 0.f, 0.f, 0.f};

    const int r = tid >> 1, h = tid & 1;
    const float* aSrc = states + (size_t)(bm + r) * DDIM + h * 16;
    const float* bSrc = Wo + (size_t)(bn + r) * DDIM + h * 16;
    unsigned short* aDst = &As[r * 40 + h * 16];
    unsigned short* bDst = &Bs[r * 40 + h * 16];

    for (int kt = 0; kt < 16; ++kt) {
        {
            float4 fa0 = *(const float4*)(aSrc + 0);
            float4 fa1 = *(const float4*)(aSrc + 4);
            float4 fa2 = *(const float4*)(aSrc + 8);
            float4 fa3 = *(const float4*)(aSrc + 12);
            union { unsigned short u[8]; s16x8 v; } pa0, pa1;
            pa0.u[0]=f2bf(fa0.x); pa0.u[1]=f2bf(fa0.y); pa0.u[2]=f2bf(fa0.z); pa0.u[3]=f2bf(fa0.w);
            pa0.u[4]=f2bf(fa1.x); pa0.u[5]=f2bf(fa1.y); pa0.u[6]=f2bf(fa1.z); pa0.u[7]=f2bf(fa1.w);
            pa1.u[0]=f2bf(fa2.x); pa1.u[1]=f2bf(fa2.y); pa1.u[2]=f2bf(fa2.z); pa1.u[3]=f2bf(fa2.w);
            pa1.u[4]=f2bf(fa3.x); pa1.u[5]=f2bf(fa3.y); pa1.u[6]=f2bf(fa3.z); pa1.u[7]=f2bf(fa3.w);
            *(s16x8*)(aDst + 0) = pa0.v;
            *(s16x8*)(aDst + 8) = pa1.v;

            float4 fb0 = *(const float4*)(bSrc + 0);
            float4 fb1 = *(const float4*)(bSrc + 4);
            float4 fb2 = *(const float4*)(bSrc + 8);
            float4 fb3 = *(const float4*)(bSrc + 12);
            union { unsigned short u[8]; s16x8 v; } pb0, pb1;
            pb0.u[0]=f2bf(fb0.x); pb0.u[1]=f2bf(fb0.y); pb0.u[2]=f2bf(fb0.z); pb0.u[3]=f2bf(fb0.w);
            pb0.u[4]=f2bf(fb1.x); pb0.u[5]=f2bf(fb1.y); pb0.u[6]=f2bf(fb1.z); pb0.u[7]=f2bf(fb1.w);
            pb1.u[0]=f2bf(fb2.x); pb1.u[1]=f2bf(fb2.y); pb1.u[2]=f2bf(fb2.z); pb1.u[3]=f2bf(fb2.w);
            pb1.u[4]=f2bf(fb3.x); pb1.u[5]=f2bf(fb3.y); pb1.u[6]=f2bf(fb3.z); pb1.u[7]=f2bf(fb3.w);
            *(s16x8*)(bDst + 0) = pb0.v;
            *(s16x8*)(bDst + 8) = pb1.v;

            aSrc += 32; bSrc += 32;
        }
        __syncthreads();

        s16x8 af[4], bf[4];
        #pragma unroll
        for (int i = 0; i < 4; ++i)
            af[i] = *(const s16x8*)&As[(wm * 64 + i * 16 + lr) * 40 + lkb];
        #pragma unroll
        for (int j = 0; j < 4; ++j)
            bf[j] = *(const s16x8*)&Bs[(wn * 64 + j * 16 + lr) * 40 + lkb];
        #pragma unroll
        for (int i = 0; i < 4; ++i)
            #pragma unroll
            for (int j = 0; j < 4; ++j)
                acc[i][j] = __builtin_amdgcn_mfma_f32_16x16x32_bf16(
                    af[i], bf[j], acc[i][j], 0, 0, 0);
        __syncthreads();
    }

    const int orow = (lane >> 4) * 4;
    #pragma unroll
    for (int i = 0; i < 4; ++i) {
        #pragma unroll
        for (int j = 0; j < 4; ++j) {
            #pragma unroll
            for (int v = 0; v < 4; ++v) {
                int m = bm + wm * 64 + i * 16 + orow + v;
                int n = bn + wn * 64 + j * 16 + lr;
                size_t idx = (size_t)m * 512 + n;
                float og = out[idx];
                out[idx] = og * (acc[i][j][v] + bo[n]);
            }
        }
    }
}

// ---------------------------------------------------------------------------
extern "C" void kernel_launch(void* const* d_in, const int* in_sizes, int n_in,
                              void* d_out, int out_size, void* d_ws, size_t ws_size,
                              hipStream_t stream)
{
    const float* x  = (const float*)d_in[0];
    const float* Wu = (const float*)d_in[1];
    const float* bu = (const float*)d_in[2];
    const float* Wt = (const float*)d_in[3];
    const float* bt = (const float*)d_in[4];
    const float* Wa = (const float*)d_in[5];
    const float* ba = (const float*)d_in[6];
    const float* Wc = (const float*)d_in[7];
    const float* bc = (const float*)d_in[8];
    const float* Wg = (const float*)d_in[9];
    const float* bg = (const float*)d_in[10];
    const float* Wo = (const float*)d_in[11];
    const float* bo = (const float*)d_in[12];
    float* out = (float*)d_out;

    // workspace layout (floats)
    float* wsf    = (float*)d_ws;
    float* gbuf   = wsf;                               // 16384*512
    float* cosb   = gbuf   + (size_t)MTOT * 512;       // 16384*256
    float* sinb   = cosb   + (size_t)MTOT * 256;       // 16384*256
    float* cdbuf  = sinb   + (size_t)MTOT * 256;       // 16384*512
    float* states = cdbuf  + (size_t)MTOT * 512;       // 16384*512
    uint2* stateTag  = (uint2*)(states + (size_t)MTOT * 512); // 8192
    uint2* xcdtag    = stateTag + 2 * BNUM * 512;             // 64
    uint2* scrubdone = xcdtag + 64;                           // 64

    clear_tags_kernel<<<(NTAGCLR + 511) / 512, 512, 0, stream>>>(stateTag);

    precompute_kernel<<<dim3(14, 128), 256, 0, stream>>>(
        x, Wu, bu, Wa, ba, Wc, bc, Wg, bg,
        gbuf, cosb, sinb, cdbuf, out /* og staged in emitted region */);

    scan_kernel<<<64, 512, 0, stream>>>(
        Wt, bt, gbuf, cosb, sinb, cdbuf,
        states, stateTag, xcdtag, scrubdone, out + (size_t)MTOT * 512);

    emit_kernel<<<dim3(4, 128), 256, 0, stream>>>(states, Wo, bo, out);
}